// Round 2
// baseline (48.459 us; speedup 1.0000x reference)
//
#include <hip/hip_runtime.h>
#include <math.h>

#define NCOL 8192
#define BT 256
#define NCHUNK 32   // 8192 / 256 elements per wave-chunk

// exact double constants
#define MZM_LOSS_D 0.8912509381337456   // 10^-0.05
#define YB_LOSS_D  0.9332543007969910   // 10^-0.03
#define MRR_LOSS_D 0.8912509381337456   // 10^-0.05

__global__ __launch_bounds__(BT)
void odp_main(const float* __restrict__ x, const float* __restrict__ w,
              const float* __restrict__ ntp, const float* __restrict__ nsp,
              const float* __restrict__ ntn, const float* __restrict__ nsn,
              float* __restrict__ out)
{
    // halo[m][0..1] = |x| at elements 256m-2, 256m-1 (left halo of chunk m)
    // halo[m][2..3] = |x| at elements 256(m+1), 256(m+1)+1 (right halo)
    __shared__ __align__(16) float halo[NCHUNK][4];
    __shared__ float  redf[8];
    __shared__ double redd[8];
    __shared__ double corrS[4];

    const int t    = threadIdx.x;
    const int lane = t & 63;
    const int wv   = t >> 6;
    const int b    = blockIdx.x;

    const float4* __restrict__ xr4 = (const float4*)(x + (size_t)b * NCOL);
    const float4* __restrict__ w4  = (const float4*)w;

    // ---- pass A: load row + weights into registers, maxes, raw halos ----
    float4 xk[8], wk[8];
    float mx = 0.f, mw = 0.f;
#pragma unroll
    for (int k = 0; k < 8; ++k) {
        xk[k] = xr4[t + BT * k];
        wk[k] = w4[t + BT * k];
        mx = fmaxf(mx, fmaxf(fmaxf(fabsf(xk[k].x), fabsf(xk[k].y)),
                             fmaxf(fabsf(xk[k].z), fabsf(xk[k].w))));
        mw = fmaxf(mw, fmaxf(fmaxf(fabsf(wk[k].x), fabsf(wk[k].y)),
                             fmaxf(fabsf(wk[k].z), fabsf(wk[k].w))));
    }
    // chunk index for (wv,k) is m = 4k+wv; lane l owns elements 4l..4l+3 of chunk m
    if (lane == 0) {
#pragma unroll
        for (int k = 0; k < 8; ++k) {
            const int m = 4 * k + wv;
            if (m > 0) { halo[m - 1][2] = fabsf(xk[k].x); halo[m - 1][3] = fabsf(xk[k].y); }
        }
    }
    if (lane == 63) {
#pragma unroll
        for (int k = 0; k < 8; ++k) {
            const int m = 4 * k + wv;
            if (m < NCHUNK - 1) { halo[m + 1][0] = fabsf(xk[k].z); halo[m + 1][1] = fabsf(xk[k].w); }
        }
    }
    if (t == 0) {   // zero-pad at row ends (conv 'SAME')
        halo[0][0] = 0.f; halo[0][1] = 0.f;
        halo[NCHUNK - 1][2] = 0.f; halo[NCHUNK - 1][3] = 0.f;
    }

#pragma unroll
    for (int off = 32; off; off >>= 1) {
        mx = fmaxf(mx, __shfl_down(mx, off));
        mw = fmaxf(mw, __shfl_down(mw, off));
    }
    if (lane == 0) { redf[wv] = mx; redf[4 + wv] = mw; }
    __syncthreads();

    float inorm = fmaxf(fmaxf(redf[0], redf[1]), fmaxf(redf[2], redf[3]));
    float wnorm = fmaxf(fmaxf(redf[4], redf[5]), fmaxf(redf[6], redf[7]));
    inorm = (inorm <= 1e-9f) ? 1.f : inorm;
    wnorm = (wnorm <= 1e-9f) ? 1.f : wnorm;
    const double inv_d = 1.0 / (double)inorm;   // emulates correctly-rounded f32 div
    const float  iwn   = 1.0f / wnorm;
    const float  CYM   = (float)(YB_LOSS_D * MZM_LOSS_D);
    const float  WS    = iwn * CYM * (10.f / 255.f);   // per-|w| scale, folds DAC+gain

    // quantize the 128 halo values in place
    if (t < NCHUNK * 4) {
        float* hf = &halo[0][0];
        hf[t] = rintf((float)((double)hf[t] * inv_d) * 255.f);
    }
    __syncthreads();

    // ---- pass C: quantize in registers, conv via shfl, accumulate ----
    double accP = 0.0, accT = 0.0, cP = 0.0, cN = 0.0;

#pragma unroll
    for (int k = 0; k < 8; ++k) {
        const int m = 4 * k + wv;
        const float4 hq  = *(const float4*)(&halo[m][0]);
        const float4 xv  = xk[k];
        const float4 wvv = wk[k];

        const float q0 = rintf((float)((double)fabsf(xv.x) * inv_d) * 255.f);
        const float q1 = rintf((float)((double)fabsf(xv.y) * inv_d) * 255.f);
        const float q2 = rintf((float)((double)fabsf(xv.z) * inv_d) * 255.f);
        const float q3 = rintf((float)((double)fabsf(xv.w) * inv_d) * 255.f);

        float Qm2 = __shfl_up(q2, 1);
        float Qm1 = __shfl_up(q3, 1);
        float Qp1 = __shfl_down(q0, 1);
        float Qp2 = __shfl_down(q1, 1);
        if (lane == 0)  { Qm2 = hq.x; Qm1 = hq.y; }
        if (lane == 63) { Qp1 = hq.z; Qp2 = hq.w; }

        const float c0 = q0 + 0.01f * (Qm1 + q1) + 0.0025f * (Qm2 + q2);
        const float c1 = q1 + 0.01f * (q0  + q2) + 0.0025f * (Qm1 + q3);
        const float c2 = q2 + 0.01f * (q1  + q3) + 0.0025f * (q0  + Qp1);
        const float c3 = q3 + 0.01f * (q2  + Qp1) + 0.0025f * (q1  + Qp2);

        const float m0 = c0 * (fabsf(wvv.x) * WS);
        const float m1 = c1 * (fabsf(wvv.y) * WS);
        const float m2 = c2 * (fabsf(wvv.z) * WS);
        const float m3 = c3 * (fabsf(wvv.w) * WS);

        const bool g0 = (xv.x > 0.f) == (wvv.x >= 0.f);
        const bool g1 = (xv.y > 0.f) == (wvv.y >= 0.f);
        const bool g2 = (xv.z > 0.f) == (wvv.z >= 0.f);
        const bool g3 = (xv.w > 0.f) == (wvv.w >= 0.f);

        const float pp = (g0 ? m0 : 0.f) + (g1 ? m1 : 0.f)
                       + (g2 ? m2 : 0.f) + (g3 ? m3 : 0.f);
        const float pt = (m0 + m1) + (m2 + m3);
        accP += (double)pp;
        accT += (double)pt;

        // row-end MRR sum-weight corrections (elements 0,1 and N-2,N-1)
        if ((k == 0 && t == 0) || (k == 7 && t == BT - 1)) {
            const double DE0 = -((double)0.01f + (double)0.0025f);
            const double DE1 = -((double)0.0025f);
            if (t == 0) {
                if (g0) cP += DE0 * (double)m0; else cN += DE0 * (double)m0;
                if (g1) cP += DE1 * (double)m1; else cN += DE1 * (double)m1;
            } else {
                if (g2) cP += DE1 * (double)m2; else cN += DE1 * (double)m2;
                if (g3) cP += DE0 * (double)m3; else cN += DE0 * (double)m3;
            }
        }
    }

    // ---- block reduce (double) + scalar tail ----
#pragma unroll
    for (int off = 32; off; off >>= 1) {
        accP += __shfl_down(accP, off);
        accT += __shfl_down(accT, off);
    }
    if (lane == 0) { redd[wv] = accP; redd[4 + wv] = accT; }
    if (t == 0)      { corrS[0] = cP; corrS[1] = cN; }
    if (t == BT - 1) { corrS[2] = cP; corrS[3] = cN; }
    __syncthreads();

    if (t == 0) {
        const double E_MID = 1.0 + 2.0 * (double)0.01f + 2.0 * (double)0.0025f;
        const double psum = (redd[0] + redd[1]) + (redd[2] + redd[3]);
        const double tsum = (redd[4] + redd[5]) + (redd[6] + redd[7]);
        const double nsum = tsum - psum;
        const double ps = (psum * E_MID + (corrS[0] + corrS[2])) * MRR_LOSS_D;
        const double ns = (nsum * E_MID + (corrS[1] + corrS[3])) * MRR_LOSS_D;

        const float thermal_f = 3.3135576e-12f;   // f32(4*kB*T*Hz/R)
        const float shot_f    = 3.204353268e-9f;  // f32(2*qE*Hz)

        double tp_ = ps + 1e-12 + (double)(ntp[b] * thermal_f);
        tp_ *= (double)(1.0f + nsp[b] * shot_f);
        double tn_ = ns + 1e-12 + (double)(ntn[b] * thermal_f);
        tn_ *= (double)(1.0f + nsn[b] * shot_f);

        const double cur = tp_ - tn_;
        double v = fabs(cur * 100.0);
        v = fmin(v, 1.0);
        const double va  = rint(v * 255.0) * (1.0 / 255.0);
        const double sgn = (cur >= 0.0) ? 1.0 : -1.0;
        const double scale = (double)wnorm /
            (10.0 * 100.0 * MRR_LOSS_D * YB_LOSS_D * MZM_LOSS_D);
        out[b] = (float)(va * sgn * scale * (double)inorm);
    }
}

extern "C" void kernel_launch(void* const* d_in, const int* in_sizes, int n_in,
                              void* d_out, int out_size, void* d_ws, size_t ws_size,
                              hipStream_t stream) {
    const float* x   = (const float*)d_in[0];
    const float* w   = (const float*)d_in[1];
    const float* ntp = (const float*)d_in[2];
    const float* nsp = (const float*)d_in[3];
    const float* ntn = (const float*)d_in[4];
    const float* nsn = (const float*)d_in[5];
    float* out = (float*)d_out;
    odp_main<<<dim3(out_size), dim3(BT), 0, stream>>>(x, w, ntp, nsp, ntn, nsn, out);
}

// Round 3
// 33.390 us; speedup vs baseline: 1.4513x; 1.4513x over previous
//
#include <hip/hip_runtime.h>
#include <math.h>

#define NCOL 8192
#define BT   512
#define EPT  16          // elements per thread
#define FPT  4           // float4 per thread

// exact double constants
#define MZM_LOSS_D 0.8912509381337456   // 10^-0.05
#define YB_LOSS_D  0.9332543007969910   // 10^-0.03
#define MRR_LOSS_D 0.8912509381337456   // 10^-0.05

__global__ __launch_bounds__(BT, 4)
void odp_main(const float* __restrict__ x, const float* __restrict__ w,
              const float* __restrict__ ntp, const float* __restrict__ nsp,
              const float* __restrict__ ntn, const float* __restrict__ nsn,
              float* __restrict__ out)
{
    __shared__ float  halo[BT][5];   // q0,q1,q14,q15 per thread (+pad, 2-way banks)
    __shared__ float  redf[16];      // [0..7] wave max|x|, [8..15] wave max|w|
    __shared__ double redd[16];      // [0..7] wave P, [8..15] wave T
    __shared__ double corrd[4];      // cP0,cT0 (t==0), cP1,cT1 (t==BT-1)

    const int t    = threadIdx.x;
    const int lane = t & 63;
    const int wid  = t >> 6;
    const int b    = blockIdx.x;

    // uniform scalar loads (compiler -> s_load), latency hidden
    const float v_ntp = ntp[b], v_nsp = nsp[b], v_ntn = ntn[b], v_nsn = nsn[b];

    const float4* __restrict__ xr4 = (const float4*)(x + (size_t)b * NCOL);
    const float4* __restrict__ w4  = (const float4*)w;

    // ---- pass A: load 16 x + 16 w into registers, block maxes ----
    float xf[EPT], wf[EPT];
    float mx = 0.f, mw = 0.f;
#pragma unroll
    for (int j = 0; j < FPT; ++j) {
        const float4 xv = xr4[t * FPT + j];
        const float4 wv = w4 [t * FPT + j];
        xf[4*j+0] = xv.x; xf[4*j+1] = xv.y; xf[4*j+2] = xv.z; xf[4*j+3] = xv.w;
        wf[4*j+0] = wv.x; wf[4*j+1] = wv.y; wf[4*j+2] = wv.z; wf[4*j+3] = wv.w;
        mx = fmaxf(mx, fmaxf(fmaxf(fabsf(xv.x), fabsf(xv.y)),
                             fmaxf(fabsf(xv.z), fabsf(xv.w))));
        mw = fmaxf(mw, fmaxf(fmaxf(fabsf(wv.x), fabsf(wv.y)),
                             fmaxf(fabsf(wv.z), fabsf(wv.w))));
    }
#pragma unroll
    for (int off = 32; off; off >>= 1) {
        mx = fmaxf(mx, __shfl_down(mx, off));
        mw = fmaxf(mw, __shfl_down(mw, off));
    }
    if (lane == 0) { redf[wid] = mx; redf[8 + wid] = mw; }
    __syncthreads();

    float inorm = redf[0], wnorm = redf[8];
#pragma unroll
    for (int i = 1; i < 8; ++i) {
        inorm = fmaxf(inorm, redf[i]);
        wnorm = fmaxf(wnorm, redf[8 + i]);
    }
    inorm = (inorm <= 1e-9f) ? 1.f : inorm;
    wnorm = (wnorm <= 1e-9f) ? 1.f : wnorm;

    // correctly-rounded f32 reciprocal of inorm (via f64), then Markstein div
    const double inv_d = 1.0 / (double)inorm;
    const float  y     = (float)inv_d;

    // ---- quantize all 16 elements (IEEE-exact f32 division semantics) ----
    float q[EPT];
#pragma unroll
    for (int c = 0; c < EPT; ++c) {
        const float a  = fabsf(xf[c]);
        const float q0 = a * y;
        const float r  = fmaf(-inorm, q0, a);
        const float t1 = fmaf(r, y, q0);          // == f32(a / inorm), Markstein
        q[c] = rintf(t1 * 255.f);
    }
    halo[t][0] = q[0]; halo[t][1] = q[1]; halo[t][2] = q[14]; halo[t][3] = q[15];
    __syncthreads();

    // splice halo into padded window Q[0..19]
    float Q[EPT + 4];
    Q[0] = (t > 0)      ? halo[t - 1][2] : 0.f;
    Q[1] = (t > 0)      ? halo[t - 1][3] : 0.f;
    Q[EPT + 2] = (t < BT - 1) ? halo[t + 1][0] : 0.f;
    Q[EPT + 3] = (t < BT - 1) ? halo[t + 1][1] : 0.f;
#pragma unroll
    for (int c = 0; c < EPT; ++c) Q[c + 2] = q[c];

    // ---- conv + masked accumulate (per-element f64, R1-faithful) ----
    const double DE0 = -((double)0.01f + (double)0.0025f);  // i=0, N-1
    const double DE1 = -((double)0.0025f);                  // i=1, N-2
    double accP = 0.0, accT = 0.0, cP = 0.0, cT = 0.0;

#pragma unroll
    for (int c = 0; c < EPT; ++c) {
        const float s1   = Q[c + 1] + Q[c + 3];
        const float s2   = Q[c]     + Q[c + 4];
        float conv = fmaf(0.01f, s1, Q[c + 2]);
        conv = fmaf(0.0025f, s2, conv);
        const float u = conv * fabsf(wf[c]);          // >= 0
        const bool  g = (xf[c] > 0.f) == (wf[c] >= 0.f);
        const double ud = (double)u;
        accT += ud;
        accP += g ? ud : 0.0;
        if ((t == 0 && c < 2) || (t == BT - 1 && c >= EPT - 2)) {
            const double de = (c == 0 || c == EPT - 1) ? DE0 : DE1;
            const double du = de * ud;
            cT += du;
            if (g) cP += du;
        }
    }

    // ---- block reduce (f64) + scalar tail ----
#pragma unroll
    for (int off = 32; off; off >>= 1) {
        accP += __shfl_down(accP, off);
        accT += __shfl_down(accT, off);
    }
    if (lane == 0)   { redd[wid] = accP; redd[8 + wid] = accT; }
    if (t == 0)      { corrd[0] = cP; corrd[1] = cT; }
    if (t == BT - 1) { corrd[2] = cP; corrd[3] = cT; }
    __syncthreads();

    if (t == 0) {
        double P = 0.0, T = 0.0;
#pragma unroll
        for (int i = 0; i < 8; ++i) { P += redd[i]; T += redd[8 + i]; }
        const double cPs = corrd[0] + corrd[2];
        const double cTs = corrd[1] + corrd[3];

        const double E_MID = 1.0 + 2.0 * (double)0.01f + 2.0 * (double)0.0025f;
        const double Kd = (10.0 / 255.0) * (YB_LOSS_D * MZM_LOSS_D) / (double)wnorm;

        const double ps = (P * E_MID + cPs) * Kd * MRR_LOSS_D;
        const double ns = ((T - P) * E_MID + (cTs - cPs)) * Kd * MRR_LOSS_D;

        const float thermal_f = 3.3135576e-12f;   // f32(4*kB*T*Hz/R)
        const float shot_f    = 3.204353268e-9f;  // f32(2*qE*Hz)

        double tp_ = ps + 1e-12 + (double)(v_ntp * thermal_f);
        tp_ *= (double)(1.0f + v_nsp * shot_f);   // == *1.0 in f32, faithful
        double tn_ = ns + 1e-12 + (double)(v_ntn * thermal_f);
        tn_ *= (double)(1.0f + v_nsn * shot_f);

        const double cur = tp_ - tn_;
        double v = fabs(cur * 100.0);
        v = fmin(v, 1.0);
        const double va  = rint(v * 255.0) * (1.0 / 255.0);
        const double sgn = (cur >= 0.0) ? 1.0 : -1.0;
        const double scale = (double)wnorm /
            (10.0 * 100.0 * MRR_LOSS_D * YB_LOSS_D * MZM_LOSS_D);
        out[b] = (float)(va * sgn * scale * (double)inorm);
    }
}

extern "C" void kernel_launch(void* const* d_in, const int* in_sizes, int n_in,
                              void* d_out, int out_size, void* d_ws, size_t ws_size,
                              hipStream_t stream) {
    const float* x   = (const float*)d_in[0];
    const float* w   = (const float*)d_in[1];
    const float* ntp = (const float*)d_in[2];
    const float* nsp = (const float*)d_in[3];
    const float* ntn = (const float*)d_in[4];
    const float* nsn = (const float*)d_in[5];
    float* out = (float*)d_out;
    odp_main<<<dim3(out_size), dim3(BT), 0, stream>>>(x, w, ntp, nsp, ntn, nsn, out);
}

// Round 4
// 30.312 us; speedup vs baseline: 1.5987x; 1.1015x over previous
//
#include <hip/hip_runtime.h>
#include <math.h>

#define NCOL 8192
#define BT   512
#define EPT  16

// exact double constants
#define MZM_LOSS_D 0.8912509381337456   // 10^-0.05
#define YB_LOSS_D  0.9332543007969910   // 10^-0.03
#define MRR_LOSS_D 0.8912509381337456   // 10^-0.05

__global__ __launch_bounds__(BT, 4)
void odp_main(const float* __restrict__ x, const float* __restrict__ w,
              const float* __restrict__ ntp, const float* __restrict__ nsp,
              const float* __restrict__ ntn, const float* __restrict__ nsn,
              float* __restrict__ out)
{
    __shared__ float  redf[16];   // [0..7] wave max|x|, [8..15] wave max|w|
    __shared__ float  redT[8];
    __shared__ double redD[8];
    __shared__ double corrd[4];   // cD(t0), cT(t0), cD(t511), cT(t511)

    const int t    = threadIdx.x;
    const int lane = t & 63;
    const int wid  = t >> 6;
    const int b    = blockIdx.x;

    const float v_ntp = ntp[b], v_nsp = nsp[b], v_ntn = ntn[b], v_nsn = nsn[b];

    const float*  __restrict__ xrow = x + (size_t)b * NCOL;
    const float4* __restrict__ xr4  = (const float4*)xrow;
    const float4* __restrict__ w4   = (const float4*)w;

    // ---- loads: own 16 x + 16 w, plus 4 halo x (clamped at row ends) ----
    float xf[EPT], wf[EPT];
    const int hL = (t > 0)      ? (t * EPT - 2)   : 0;          // 8B-aligned
    const int hR = (t < BT - 1) ? (t * EPT + EPT) : (NCOL - 2); // 8B-aligned
    const float2 hxL = *(const float2*)(xrow + hL);
    const float2 hxR = *(const float2*)(xrow + hR);

    float mx = 0.f, mw = 0.f;
#pragma unroll
    for (int j = 0; j < 4; ++j) {
        const float4 xv = xr4[t * 4 + j];
        const float4 wv = w4 [t * 4 + j];
        xf[4*j+0]=xv.x; xf[4*j+1]=xv.y; xf[4*j+2]=xv.z; xf[4*j+3]=xv.w;
        wf[4*j+0]=wv.x; wf[4*j+1]=wv.y; wf[4*j+2]=wv.z; wf[4*j+3]=wv.w;
        mx = fmaxf(mx, fmaxf(fmaxf(fabsf(xv.x), fabsf(xv.y)),
                             fmaxf(fabsf(xv.z), fabsf(xv.w))));
        mw = fmaxf(mw, fmaxf(fmaxf(fabsf(wv.x), fabsf(wv.y)),
                             fmaxf(fabsf(wv.z), fabsf(wv.w))));
    }
#pragma unroll
    for (int off = 32; off; off >>= 1) {
        mx = fmaxf(mx, __shfl_down(mx, off));
        mw = fmaxf(mw, __shfl_down(mw, off));
    }
    if (lane == 0) { redf[wid] = mx; redf[8 + wid] = mw; }
    __syncthreads();

    float inorm = redf[0], wnorm = redf[8];
#pragma unroll
    for (int i = 1; i < 8; ++i) {
        inorm = fmaxf(inorm, redf[i]);
        wnorm = fmaxf(wnorm, redf[8 + i]);
    }
    inorm = (inorm <= 1e-9f) ? 1.f : inorm;
    wnorm = (wnorm <= 1e-9f) ? 1.f : wnorm;

    // correctly-rounded f32 reciprocal (via f64); Markstein => exact f32 div
    const double inv_d = 1.0 / (double)inorm;
    const float  y     = (float)inv_d;

    // ---- quantize own 16 + 4 halo (IEEE f32-div exact) ----
    float Q[EPT + 4];
#pragma unroll
    for (int c = 0; c < EPT; ++c) {
        const float a  = fabsf(xf[c]);
        const float q0 = a * y;
        const float r  = fmaf(-inorm, q0, a);
        Q[c + 2] = rintf(fmaf(r, y, q0) * 255.f);
    }
    {
        const float aL0 = fabsf(hxL.x), aL1 = fabsf(hxL.y);
        const float aR0 = fabsf(hxR.x), aR1 = fabsf(hxR.y);
        float q0, r;
        q0 = aL0 * y; r = fmaf(-inorm, q0, aL0); Q[0]  = rintf(fmaf(r, y, q0) * 255.f);
        q0 = aL1 * y; r = fmaf(-inorm, q0, aL1); Q[1]  = rintf(fmaf(r, y, q0) * 255.f);
        q0 = aR0 * y; r = fmaf(-inorm, q0, aR0); Q[18] = rintf(fmaf(r, y, q0) * 255.f);
        q0 = aR1 * y; r = fmaf(-inorm, q0, aR1); Q[19] = rintf(fmaf(r, y, q0) * 255.f);
        if (t == 0)      { Q[0]  = 0.f; Q[1]  = 0.f; }   // conv 'SAME' zero pad
        if (t == BT - 1) { Q[18] = 0.f; Q[19] = 0.f; }
    }

    // ---- conv + D/T accumulate (4 rotating f32 chains) ----
    float Dv[4] = {0.f,0.f,0.f,0.f}, Tv[4] = {0.f,0.f,0.f,0.f};
    double cD = 0.0, cT = 0.0;
    const double DE0 = -((double)0.01f + (double)0.0025f);  // i = 0, N-1
    const double DE1 = -((double)0.0025f);                  // i = 1, N-2

#pragma unroll
    for (int c = 0; c < EPT; ++c) {
        const float s1 = Q[c + 1] + Q[c + 3];
        const float s2 = Q[c]     + Q[c + 4];
        float conv = fmaf(0.01f, s1, Q[c + 2]);
        conv = fmaf(0.0025f, s2, conv);
        const float sel = (xf[c] > 0.f) ? wf[c] : -wf[c];   // cmp + cndmask(-mod)
        Dv[c & 3] = fmaf(conv, sel,        Dv[c & 3]);
        Tv[c & 3] = fmaf(conv, fabsf(sel), Tv[c & 3]);      // |sel| = |w|, free mod
        if (t == 0 && c < 2) {
            const double de = (c == 0) ? DE0 : DE1;
            cD += de * (double)(conv * sel);
            cT += de * (double)(conv * fabsf(sel));
        }
        if (t == BT - 1 && c >= EPT - 2) {
            const double de = (c == EPT - 1) ? DE0 : DE1;
            cD += de * (double)(conv * sel);
            cT += de * (double)(conv * fabsf(sel));
        }
    }

    double accD = ((double)Dv[0] + (double)Dv[1]) + ((double)Dv[2] + (double)Dv[3]);
    float  accT = (Tv[0] + Tv[1]) + (Tv[2] + Tv[3]);

    // ---- block reduce: D in f64, T in f32 ----
#pragma unroll
    for (int off = 32; off; off >>= 1) {
        accD += __shfl_down(accD, off);
        accT += __shfl_down(accT, off);
    }
    if (lane == 0)   { redD[wid] = accD; redT[wid] = accT; }
    if (t == 0)      { corrd[0] = cD; corrd[1] = cT; }
    if (t == BT - 1) { corrd[2] = cD; corrd[3] = cT; }
    __syncthreads();

    if (t == 0) {
        double D = 0.0, T = 0.0;
#pragma unroll
        for (int i = 0; i < 8; ++i) { D += redD[i]; T += (double)redT[i]; }
        const double E_MID = 1.0 + 2.0 * (double)0.01f + 2.0 * (double)0.0025f;
        D = D * E_MID + (corrd[0] + corrd[2]);
        T = T * E_MID + (corrd[1] + corrd[3]);

        const double Kd = (10.0 / 255.0) * (YB_LOSS_D * MZM_LOSS_D) / (double)wnorm;
        const double ps = (T + D) * 0.5 * Kd * MRR_LOSS_D;
        const double ns = (T - D) * 0.5 * Kd * MRR_LOSS_D;

        const float thermal_f = 3.3135576e-12f;   // f32(4*kB*T*Hz/R)
        const float shot_f    = 3.204353268e-9f;  // f32(2*qE*Hz)

        double tp_ = ps + 1e-12 + (double)(v_ntp * thermal_f);
        tp_ *= (double)(1.0f + v_nsp * shot_f);   // == *1.0 in f32, faithful
        double tn_ = ns + 1e-12 + (double)(v_ntn * thermal_f);
        tn_ *= (double)(1.0f + v_nsn * shot_f);

        const double cur = tp_ - tn_;
        double v = fabs(cur * 100.0);
        v = fmin(v, 1.0);
        const double va  = rint(v * 255.0) * (1.0 / 255.0);
        const double sgn = (cur >= 0.0) ? 1.0 : -1.0;
        const double scale = (double)wnorm /
            (10.0 * 100.0 * MRR_LOSS_D * YB_LOSS_D * MZM_LOSS_D);
        out[b] = (float)(va * sgn * scale * (double)inorm);
    }
}

extern "C" void kernel_launch(void* const* d_in, const int* in_sizes, int n_in,
                              void* d_out, int out_size, void* d_ws, size_t ws_size,
                              hipStream_t stream) {
    const float* x   = (const float*)d_in[0];
    const float* w   = (const float*)d_in[1];
    const float* ntp = (const float*)d_in[2];
    const float* nsp = (const float*)d_in[3];
    const float* ntn = (const float*)d_in[4];
    const float* nsn = (const float*)d_in[5];
    float* out = (float*)d_out;
    odp_main<<<dim3(out_size), dim3(BT), 0, stream>>>(x, w, ntp, nsp, ntn, nsn, out);
}